// Round 2
// baseline (1691.895 us; speedup 1.0000x reference)
//
#include <hip/hip_runtime.h>
#include <hip/hip_cooperative_groups.h>
#include <cstddef>

#define EPSV 0.1f
#define INV_EPS 10.0f
#define THRESHV 0.1f
#define MAX_ITER 100
// log(1/2048 + 1e-8)
#define LOG_MU_NU (-7.6245985f)

typedef _Float16 half2_t __attribute__((ext_vector_type(2)));
typedef _Float16 half4_t __attribute__((ext_vector_type(4)));
typedef _Float16 half8_t __attribute__((ext_vector_type(8)));

// ---- workspace layout (float offsets) ----
#define WS_U 0
#define WS_V 16384
#define WS_X2 32768
#define WS_Y2 49152
#define WS_ERR 65536
#define WS_DONE 65537  // int: iteration index at which convergence triggered (INT_MAX = not yet)
// fp16 copy of C lives at byte offset WS_C16_BYTE (64-byte aligned); transposed copy follows
#define WS_C16_BYTE 327680ull
#define C16_BYTES (33554432ull * 2ull)
#define WS_CT_BYTE (WS_C16_BYTE + C16_BYTES)

// ---- output layout (float offsets): dis[8][2048], cost[8], pi[8][2048][2048], C[8][2048][2048]
#define OUT_DIS 0
#define OUT_COST 16384
#define OUT_PI 16392ull
#define OUT_C 33570824ull

__device__ __forceinline__ int load_done(const float* ws) {
    return __hip_atomic_load((int*)ws + WS_DONE, __ATOMIC_RELAXED, __HIP_MEMORY_SCOPE_AGENT);
}

__device__ __forceinline__ void check_prologue(float* ws, int it) {
    if (blockIdx.x == 0 && threadIdx.x == 0) {
        float e = ws[WS_ERR] * (1.0f / 8.0f);
        if (e < THRESHV)
            __hip_atomic_store((int*)ws + WS_DONE, it, __ATOMIC_RELAXED, __HIP_MEMORY_SCOPE_AGENT);
        ws[WS_ERR] = 0.f;
    }
}

// ---------------- init: zero u, v, err, dis, cost; done_iter = INT_MAX ----------------
__global__ void k_init(float* __restrict__ ws, float* __restrict__ out) {
    int idx = blockIdx.x * 256 + threadIdx.x;
    if (idx < 16384) {
        ws[WS_U + idx] = 0.f;
        ws[WS_V + idx] = 0.f;
        out[OUT_DIS + idx] = 0.f;
    }
    if (idx < 8) out[OUT_COST + idx] = 0.f;
    if (idx == 0) {
        ws[WS_ERR] = 0.f;
        ((int*)ws)[WS_DONE] = 0x7fffffff;
    }
}

// ---------------- x2 / y2: mean of squares over D=64 ----------------
__global__ __launch_bounds__(256) void k_sqnorm(const float* __restrict__ x,
                                                const float* __restrict__ y,
                                                float* __restrict__ ws) {
    int gid = blockIdx.x * 256 + threadIdx.x;
    int row = gid >> 4;
    int l = gid & 15;
    const float* src = (row < 16384) ? x : y;
    int r = row & 16383;
    float4 f = ((const float4*)(src + ((size_t)r << 6)))[l];
    float s = f.x * f.x + f.y * f.y + f.z * f.z + f.w * f.w;
    s += __shfl_xor(s, 1);
    s += __shfl_xor(s, 2);
    s += __shfl_xor(s, 4);
    s += __shfl_xor(s, 8);
    if (l == 0) ws[WS_X2 + row] = s * (1.0f / 64.0f);
}

// ---------------- C = x2_i + y2_j - (2/D) x.y^T  (+ fp16 copy, + transposed fp16 copy) ----------------
__global__ __launch_bounds__(256) void k_gemm(const float* __restrict__ x,
                                              const float* __restrict__ y,
                                              const float* __restrict__ ws,
                                              float* __restrict__ out,
                                              _Float16* __restrict__ c16,
                                              _Float16* __restrict__ c16T) {
    __shared__ float xsT[64][68];
    __shared__ float ysT[64][68];
    int b = blockIdx.z;
    int i0 = blockIdx.y * 64, j0 = blockIdx.x * 64;
    int t = threadIdx.x;
    const float* xb = x + ((size_t)b << 17);
    const float* yb = y + ((size_t)b << 17);
#pragma unroll
    for (int l = 0; l < 4; ++l) {
        int idx = l * 256 + t;
        int row = idx >> 4, kq = idx & 15;
        float4 fx = ((const float4*)(xb + ((size_t)(i0 + row) << 6)))[kq];
        xsT[kq * 4 + 0][row] = fx.x;
        xsT[kq * 4 + 1][row] = fx.y;
        xsT[kq * 4 + 2][row] = fx.z;
        xsT[kq * 4 + 3][row] = fx.w;
        float4 fy = ((const float4*)(yb + ((size_t)(j0 + row) << 6)))[kq];
        ysT[kq * 4 + 0][row] = fy.x;
        ysT[kq * 4 + 1][row] = fy.y;
        ysT[kq * 4 + 2][row] = fy.z;
        ysT[kq * 4 + 3][row] = fy.w;
    }
    __syncthreads();
    int tx = t & 15, ty = t >> 4;
    float acc[4][4] = {};
#pragma unroll 4
    for (int k = 0; k < 64; ++k) {
        float4 xa = *(const float4*)(&xsT[k][ty << 2]);
        float4 yv = *(const float4*)(&ysT[k][tx << 2]);
        float xr[4] = {xa.x, xa.y, xa.z, xa.w};
        float yc[4] = {yv.x, yv.y, yv.z, yv.w};
#pragma unroll
        for (int r = 0; r < 4; ++r)
#pragma unroll
            for (int c = 0; c < 4; ++c) acc[r][c] = fmaf(xr[r], yc[c], acc[r][c]);
    }
    const float* x2 = ws + WS_X2;
    const float* y2 = ws + WS_Y2;
    float x2r[4], y2c[4];
#pragma unroll
    for (int r = 0; r < 4; ++r) x2r[r] = x2[b * 2048 + i0 + ty * 4 + r];
#pragma unroll
    for (int c = 0; c < 4; ++c) y2c[c] = y2[b * 2048 + j0 + tx * 4 + c];
    float cvf[4][4];
#pragma unroll
    for (int r = 0; r < 4; ++r)
#pragma unroll
        for (int c = 0; c < 4; ++c) cvf[r][c] = x2r[r] + y2c[c] - acc[r][c] * (2.0f / 64.0f);

    float* C = out + OUT_C;
#pragma unroll
    for (int r = 0; r < 4; ++r) {
        int i = i0 + ty * 4 + r;
        float4 cv;
        cv.x = cvf[r][0];
        cv.y = cvf[r][1];
        cv.z = cvf[r][2];
        cv.w = cvf[r][3];
        size_t eoff = ((((size_t)b << 11) + i) << 11) + j0 + tx * 4;
        *(float4*)(C + eoff) = cv;
        if (c16) {
            half4_t h;
            h[0] = (_Float16)cv.x;
            h[1] = (_Float16)cv.y;
            h[2] = (_Float16)cv.z;
            h[3] = (_Float16)cv.w;
            *(half4_t*)(c16 + eoff) = h;
        }
    }
    // transposed fp16 copy: CT[b][j][i]
    if (c16T) {
#pragma unroll
        for (int c = 0; c < 4; ++c) {
            half4_t h;
            h[0] = (_Float16)cvf[0][c];
            h[1] = (_Float16)cvf[1][c];
            h[2] = (_Float16)cvf[2][c];
            h[3] = (_Float16)cvf[3][c];
            size_t toff = (((size_t)(b << 11) + j0 + tx * 4 + c) << 11) + i0 + ty * 4;
            *(half4_t*)(c16T + toff) = h;
        }
    }
}

// ---- one-row LSE: wave computes eps*(log_mu - logsumexp((d - C_row)/eps)) ----
// Returned in ALL lanes (m, s are wave-reduced).
__device__ __forceinline__ float lse_row(const _Float16* __restrict__ Crow16,
                                         const float* __restrict__ dvec, int lane) {
    const half8_t* Crow = (const half8_t*)Crow16;
    const float4* db = (const float4*)dvec;
    float a[32];
    float m = -1e30f;
#pragma unroll
    for (int c = 0; c < 4; ++c) {
        int base = (c << 6) + lane;
        half8_t ch = Crow[base];
        float4 f0 = db[2 * base];
        float4 f1 = db[2 * base + 1];
        float* ap = a + (c << 3);
        ap[0] = (f0.x - (float)ch[0]) * INV_EPS;
        ap[1] = (f0.y - (float)ch[1]) * INV_EPS;
        ap[2] = (f0.z - (float)ch[2]) * INV_EPS;
        ap[3] = (f0.w - (float)ch[3]) * INV_EPS;
        ap[4] = (f1.x - (float)ch[4]) * INV_EPS;
        ap[5] = (f1.y - (float)ch[5]) * INV_EPS;
        ap[6] = (f1.z - (float)ch[6]) * INV_EPS;
        ap[7] = (f1.w - (float)ch[7]) * INV_EPS;
#pragma unroll
        for (int q = 0; q < 8; ++q) m = fmaxf(m, ap[q]);
    }
#pragma unroll
    for (int off = 1; off < 64; off <<= 1) m = fmaxf(m, __shfl_xor(m, off));
    float s = 0.f;
#pragma unroll
    for (int q = 0; q < 32; ++q) s += __expf(a[q] - m);
#pragma unroll
    for (int off = 1; off < 64; off <<= 1) s += __shfl_xor(s, off);
    return EPSV * (LOG_MU_NU - m - __logf(s));
}

// ---------------- persistent cooperative Sinkhorn loop ----------------
// 1024 blocks x 256 thr (4 blocks/CU guaranteed by launch_bounds), 4096 waves,
// 4 rows/wave per phase. Entire iteration loop in one dispatch; converged -> break.
__global__ __launch_bounds__(256, 4) void k_sink(const _Float16* __restrict__ C16,
                                                 const _Float16* __restrict__ CT,
                                                 float* __restrict__ ws) {
    cooperative_groups::grid_group grid = cooperative_groups::this_grid();
    float* u = ws + WS_U;
    float* v = ws + WS_V;
    float* err = ws + WS_ERR;
    int* done = (int*)ws + WS_DONE;
    int gw = (blockIdx.x * 256 + threadIdx.x) >> 6;
    int lane = threadIdx.x & 63;
    bool checker = (blockIdx.x == 0 && threadIdx.x == 0);
    for (int it = 0; it < MAX_ITER; ++it) {
        // watermark: set at iteration k -> iterations > k frozen. Uniform across grid
        // (written before the previous grid.sync).
        if (__hip_atomic_load(done, __ATOMIC_RELAXED, __HIP_MEMORY_SCOPE_AGENT) < it) break;
        // ---- u phase ----
        float eacc = 0.f;
        for (int r = gw; r < 16384; r += 4096) {
            int b = r >> 11;
            float unew = lse_row(C16 + ((size_t)r << 11), v + (b << 11), lane);
            if (lane == 0) {
                eacc += fabsf(unew - u[r]);
                u[r] = unew;
            }
        }
        if (lane == 0) atomicAdd(err, eacc);
        grid.sync();
        // ---- convergence check (err complete) + v phase ----
        if (checker) {
            if (ws[WS_ERR] * (1.0f / 8.0f) < THRESHV)
                __hip_atomic_store(done, it, __ATOMIC_RELAXED, __HIP_MEMORY_SCOPE_AGENT);
            ws[WS_ERR] = 0.f;
        }
        for (int r = gw; r < 16384; r += 4096) {
            int b = r >> 11;
            float vnew = lse_row(CT + ((size_t)r << 11), u + (b << 11), lane);
            if (lane == 0) v[r] = vnew;
        }
        grid.sync();
    }
}

// ---------------- per-launch iteration kernels (fallback if cooperative launch fails) ----------------
__global__ __launch_bounds__(256) void k_urow16(const _Float16* __restrict__ C16,
                                                float* __restrict__ ws, int it) {
    if (load_done(ws) < it) return;
    float* u = ws + WS_U;
    const float* v = ws + WS_V;
    float* err = ws + WS_ERR;
    int gw = (blockIdx.x * 256 + threadIdx.x) >> 6;
    int lane = threadIdx.x & 63;
    float eacc = 0.f;
    for (int r = gw; r < 16384; r += 4096) {
        int b = r >> 11;
        float unew = lse_row(C16 + ((size_t)r << 11), v + (b << 11), lane);
        if (lane == 0) {
            eacc += fabsf(unew - u[r]);
            u[r] = unew;
        }
    }
    if (lane == 0) atomicAdd(err, eacc);
}

__global__ __launch_bounds__(256) void k_vrow16(const _Float16* __restrict__ CT,
                                                float* __restrict__ ws, int it) {
    if (load_done(ws) < it) return;
    check_prologue(ws, it);
    const float* u = ws + WS_U;
    float* v = ws + WS_V;
    int gw = (blockIdx.x * 256 + threadIdx.x) >> 6;
    int lane = threadIdx.x & 63;
    for (int r = gw; r < 16384; r += 4096) {
        int b = r >> 11;
        float vnew = lse_row(CT + ((size_t)r << 11), u + (b << 11), lane);
        if (lane == 0) v[r] = vnew;
    }
}

// ---------------- fallback fp32 iteration kernels (small ws) ----------------
__global__ __launch_bounds__(256) void k_urow(const float* __restrict__ out,
                                              float* __restrict__ ws, int it) {
    if (load_done(ws) < it) return;
    float* u = ws + WS_U;
    const float* v = ws + WS_V;
    float* err = ws + WS_ERR;
    const float* C = out + OUT_C;
    int gw = (blockIdx.x * 256 + threadIdx.x) >> 6;
    int lane = threadIdx.x & 63;
    float eacc = 0.f;
    for (int r = gw; r < 16384; r += 4096) {
        int b = r >> 11;
        const float4* Crow = (const float4*)(C + ((size_t)r << 11));
        const float4* vb = (const float4*)(v + (b << 11));
        float a[32];
        float m = -1e30f;
#pragma unroll
        for (int c = 0; c < 8; ++c) {
            float4 cf = Crow[(c << 6) + lane];
            float4 vf = vb[(c << 6) + lane];
            a[4 * c + 0] = (vf.x - cf.x) * INV_EPS;
            a[4 * c + 1] = (vf.y - cf.y) * INV_EPS;
            a[4 * c + 2] = (vf.z - cf.z) * INV_EPS;
            a[4 * c + 3] = (vf.w - cf.w) * INV_EPS;
            m = fmaxf(m, fmaxf(fmaxf(a[4 * c + 0], a[4 * c + 1]), fmaxf(a[4 * c + 2], a[4 * c + 3])));
        }
#pragma unroll
        for (int off = 1; off < 64; off <<= 1) m = fmaxf(m, __shfl_xor(m, off));
        float s = 0.f;
#pragma unroll
        for (int q = 0; q < 32; ++q) s += __expf(a[q] - m);
#pragma unroll
        for (int off = 1; off < 64; off <<= 1) s += __shfl_xor(s, off);
        float unew = EPSV * (LOG_MU_NU - m - __logf(s));
        if (lane == 0) {
            eacc += fabsf(unew - u[r]);
            u[r] = unew;
        }
    }
    if (lane == 0) atomicAdd(err, eacc);
}

__global__ __launch_bounds__(256) void k_vcol(const float* __restrict__ out,
                                              float* __restrict__ ws, int it) {
    if (load_done(ws) < it) return;
    check_prologue(ws, it);
    const float* u = ws + WS_U;
    float* v = ws + WS_V;
    __shared__ float lm[8][33];
    __shared__ float ls[8][33];
    int b = blockIdx.x >> 6;
    int cg = blockIdx.x & 63;
    int j0 = cg * 32;
    int t = threadIdx.x;
    int jl = t & 31, chunk = t >> 5;
    const float* Cc = out + OUT_C + ((size_t)b << 22) + j0 + jl;
    const float* ub = u + (b << 11);
    float m = -1e30f, s = 0.f;
    int ibase = chunk << 8;
#pragma unroll 4
    for (int ii = 0; ii < 256; ++ii) {
        int i = ibase + ii;
        float xv = (ub[i] - Cc[(size_t)i << 11]) * INV_EPS;
        float nm = fmaxf(m, xv);
        s = s * __expf(m - nm) + __expf(xv - nm);
        m = nm;
    }
    lm[chunk][jl] = m;
    ls[chunk][jl] = s;
    __syncthreads();
    if (t < 32) {
        float M = -1e30f;
#pragma unroll
        for (int c = 0; c < 8; ++c) M = fmaxf(M, lm[c][t]);
        float S = 0.f;
#pragma unroll
        for (int c = 0; c < 8; ++c) S += ls[c][t] * __expf(lm[c][t] - M);
        v[(b << 11) + j0 + t] = EPSV * (LOG_MU_NU - M - __logf(S));
    }
}

// ---------------- epilogue: pi, dis (uses exact fp32 C) ----------------
__global__ __launch_bounds__(256) void k_epi(float* __restrict__ out, const float* __restrict__ ws) {
    int b = blockIdx.z, jg = blockIdx.x, ic = blockIdx.y;
    int j = jg * 256 + threadIdx.x;
    int i0 = ic * 128;
    const float* u = ws + WS_U;
    const float* v = ws + WS_V;
    const float* C = out + OUT_C + ((size_t)b << 22);
    float* pi = out + OUT_PI + ((size_t)b << 22);
    float vj = v[(b << 11) + j];
    float accd = 0.f;
#pragma unroll 4
    for (int r = 0; r < 128; ++r) {
        int i = i0 + r;
        size_t idx = ((size_t)i << 11) + j;
        float cv = C[idx];
        float p = __expf((u[(b << 11) + i] + vj - cv) * INV_EPS);
        pi[idx] = p;
        accd = fmaf(p, cv, accd);
    }
    atomicAdd(out + OUT_DIS + (b << 11) + j, accd);
}

// ---------------- cost_b = sum_j dis_bj ----------------
__global__ void k_cost(float* __restrict__ out) {
    int b = blockIdx.x;
    float s = 0.f;
    for (int j = threadIdx.x; j < 2048; j += 256) s += out[OUT_DIS + (b << 11) + j];
#pragma unroll
    for (int off = 1; off < 64; off <<= 1) s += __shfl_xor(s, off);
    __shared__ float red[4];
    if ((threadIdx.x & 63) == 0) red[threadIdx.x >> 6] = s;
    __syncthreads();
    if (threadIdx.x == 0) out[OUT_COST + b] = red[0] + red[1] + red[2] + red[3];
}

extern "C" void kernel_launch(void* const* d_in, const int* in_sizes, int n_in,
                              void* d_out, int out_size, void* d_ws, size_t ws_size,
                              hipStream_t stream) {
    const float* x = (const float*)d_in[0];
    const float* y = (const float*)d_in[1];
    float* out = (float*)d_out;
    float* ws = (float*)d_ws;

    bool use16 = ws_size >= WS_C16_BYTE + C16_BYTES;
    bool useCT = ws_size >= WS_CT_BYTE + C16_BYTES;
    _Float16* c16 = use16 ? (_Float16*)((char*)d_ws + WS_C16_BYTE) : nullptr;
    _Float16* c16T = useCT ? (_Float16*)((char*)d_ws + WS_CT_BYTE) : nullptr;

    k_init<<<64, 256, 0, stream>>>(ws, out);
    k_sqnorm<<<2048, 256, 0, stream>>>(x, y, ws);
    k_gemm<<<dim3(32, 32, 8), 256, 0, stream>>>(x, y, ws, out, c16, c16T);

    bool coop_ok = false;
    if (useCT) {
        void* args[] = {(void*)&c16, (void*)&c16T, (void*)&ws};
        hipError_t e = hipLaunchCooperativeKernel((const void*)k_sink, dim3(1024), dim3(256),
                                                  args, 0, stream);
        coop_ok = (e == hipSuccess);
    }
    if (!coop_ok) {
        for (int it = 0; it < MAX_ITER; ++it) {
            if (useCT) {
                k_urow16<<<1024, 256, 0, stream>>>(c16, ws, it);
                k_vrow16<<<1024, 256, 0, stream>>>(c16T, ws, it);
            } else {
                k_urow<<<1024, 256, 0, stream>>>(out, ws, it);
                k_vcol<<<512, 256, 0, stream>>>(out, ws, it);
            }
        }
    }
    k_epi<<<dim3(8, 16, 8), 256, 0, stream>>>(out, ws);
    k_cost<<<8, 256, 0, stream>>>(out);
}

// Round 3
// 1202.402 us; speedup vs baseline: 1.4071x; 1.4071x over previous
//
#include <hip/hip_runtime.h>
#include <cstddef>

#define EPSV 0.1f
#define INV_EPS 10.0f
#define THRESHV 0.1f
#define MAX_ITER 100
// log(1/2048 + 1e-8)
#define LOG_MU_NU (-7.6245985f)

typedef _Float16 half4_t __attribute__((ext_vector_type(4)));
typedef _Float16 half8_t __attribute__((ext_vector_type(8)));

// ---- workspace layout (float offsets) ----
#define WS_U 0
#define WS_V 16384
#define WS_X2 32768
#define WS_Y2 49152
#define WS_ERR 65536
#define WS_DONE 65537  // int: iteration index at which convergence triggered (INT_MAX = not yet)
#define WS_C16_BYTE 327680ull
#define C16_BYTES (33554432ull * 2ull)
#define WS_CT_BYTE (WS_C16_BYTE + C16_BYTES)

// ---- output layout (float offsets): dis[8][2048], cost[8], pi[8][2048][2048], C[8][2048][2048]
#define OUT_DIS 0
#define OUT_COST 16384
#define OUT_PI 16392ull
#define OUT_C 33570824ull

__device__ __forceinline__ int load_done(const float* ws) {
    return __hip_atomic_load((int*)ws + WS_DONE, __ATOMIC_RELAXED, __HIP_MEMORY_SCOPE_AGENT);
}

// Convergence check in v-kernel prologue: err was finalized by the u-kernel (previous
// dispatch). Benign race: at the triggering iteration both INT_MAX and `it` fail the
// `< it` early-exit, so v still commits this iteration (matches reference).
__device__ __forceinline__ void check_prologue(float* ws, int it) {
    if (blockIdx.x == 0 && threadIdx.x == 0) {
        float e = ws[WS_ERR] * (1.0f / 8.0f);
        if (e < THRESHV)
            __hip_atomic_store((int*)ws + WS_DONE, it, __ATOMIC_RELAXED, __HIP_MEMORY_SCOPE_AGENT);
        ws[WS_ERR] = 0.f;
    }
}

// ---------------- init ----------------
__global__ void k_init(float* __restrict__ ws, float* __restrict__ out) {
    int idx = blockIdx.x * 256 + threadIdx.x;
    if (idx < 16384) {
        ws[WS_U + idx] = 0.f;
        ws[WS_V + idx] = 0.f;
        out[OUT_DIS + idx] = 0.f;
    }
    if (idx < 8) out[OUT_COST + idx] = 0.f;
    if (idx == 0) {
        ws[WS_ERR] = 0.f;
        ((int*)ws)[WS_DONE] = 0x7fffffff;
    }
}

// ---------------- x2 / y2: mean of squares over D=64 ----------------
__global__ __launch_bounds__(256) void k_sqnorm(const float* __restrict__ x,
                                                const float* __restrict__ y,
                                                float* __restrict__ ws) {
    int gid = blockIdx.x * 256 + threadIdx.x;
    int row = gid >> 4;
    int l = gid & 15;
    const float* src = (row < 16384) ? x : y;
    int r = row & 16383;
    float4 f = ((const float4*)(src + ((size_t)r << 6)))[l];
    float s = f.x * f.x + f.y * f.y + f.z * f.z + f.w * f.w;
    s += __shfl_xor(s, 1);
    s += __shfl_xor(s, 2);
    s += __shfl_xor(s, 4);
    s += __shfl_xor(s, 8);
    if (l == 0) ws[WS_X2 + row] = s * (1.0f / 64.0f);
}

// ---------------- k_gemm: C16 + CT (fp16); fp32 C only in fallback mode ----------------
__global__ __launch_bounds__(256) void k_gemm(const float* __restrict__ x,
                                              const float* __restrict__ y,
                                              const float* __restrict__ ws,
                                              float* __restrict__ out,
                                              _Float16* __restrict__ c16,
                                              _Float16* __restrict__ c16T,
                                              int wc32) {
    __shared__ float xsT[64][68];
    __shared__ float ysT[64][68];
    int b = blockIdx.z;
    int i0 = blockIdx.y * 64, j0 = blockIdx.x * 64;
    int t = threadIdx.x;
    const float* xb = x + ((size_t)b << 17);
    const float* yb = y + ((size_t)b << 17);
#pragma unroll
    for (int l = 0; l < 4; ++l) {
        int idx = l * 256 + t;
        int row = idx >> 4, kq = idx & 15;
        float4 fx = ((const float4*)(xb + ((size_t)(i0 + row) << 6)))[kq];
        xsT[kq * 4 + 0][row] = fx.x;
        xsT[kq * 4 + 1][row] = fx.y;
        xsT[kq * 4 + 2][row] = fx.z;
        xsT[kq * 4 + 3][row] = fx.w;
        float4 fy = ((const float4*)(yb + ((size_t)(j0 + row) << 6)))[kq];
        ysT[kq * 4 + 0][row] = fy.x;
        ysT[kq * 4 + 1][row] = fy.y;
        ysT[kq * 4 + 2][row] = fy.z;
        ysT[kq * 4 + 3][row] = fy.w;
    }
    __syncthreads();
    int tx = t & 15, ty = t >> 4;
    float acc[4][4] = {};
#pragma unroll 4
    for (int k = 0; k < 64; ++k) {
        float4 xa = *(const float4*)(&xsT[k][ty << 2]);
        float4 yv = *(const float4*)(&ysT[k][tx << 2]);
        float xr[4] = {xa.x, xa.y, xa.z, xa.w};
        float yc[4] = {yv.x, yv.y, yv.z, yv.w};
#pragma unroll
        for (int r = 0; r < 4; ++r)
#pragma unroll
            for (int c = 0; c < 4; ++c) acc[r][c] = fmaf(xr[r], yc[c], acc[r][c]);
    }
    const float* x2 = ws + WS_X2;
    const float* y2 = ws + WS_Y2;
    float x2r[4], y2c[4];
#pragma unroll
    for (int r = 0; r < 4; ++r) x2r[r] = x2[b * 2048 + i0 + ty * 4 + r];
#pragma unroll
    for (int c = 0; c < 4; ++c) y2c[c] = y2[b * 2048 + j0 + tx * 4 + c];
    float cvf[4][4];
#pragma unroll
    for (int r = 0; r < 4; ++r)
#pragma unroll
        for (int c = 0; c < 4; ++c) cvf[r][c] = x2r[r] + y2c[c] - acc[r][c] * (2.0f / 64.0f);

    float* C = out + OUT_C;
#pragma unroll
    for (int r = 0; r < 4; ++r) {
        int i = i0 + ty * 4 + r;
        size_t eoff = ((((size_t)b << 11) + i) << 11) + j0 + tx * 4;
        if (wc32) {
            float4 cv;
            cv.x = cvf[r][0];
            cv.y = cvf[r][1];
            cv.z = cvf[r][2];
            cv.w = cvf[r][3];
            *(float4*)(C + eoff) = cv;
        }
        if (c16) {
            half4_t h;
            h[0] = (_Float16)cvf[r][0];
            h[1] = (_Float16)cvf[r][1];
            h[2] = (_Float16)cvf[r][2];
            h[3] = (_Float16)cvf[r][3];
            *(half4_t*)(c16 + eoff) = h;
        }
    }
    if (c16T) {
#pragma unroll
        for (int c = 0; c < 4; ++c) {
            half4_t h;
            h[0] = (_Float16)cvf[0][c];
            h[1] = (_Float16)cvf[1][c];
            h[2] = (_Float16)cvf[2][c];
            h[3] = (_Float16)cvf[3][c];
            size_t toff = (((size_t)(b << 11) + j0 + tx * 4 + c) << 11) + i0 + ty * 4;
            *(half4_t*)(c16T + toff) = h;
        }
    }
}

// ---- one-row LSE; dvec comes from LDS (inlined -> addrspace known, ds_read_b128) ----
__device__ __forceinline__ float lse_row(const _Float16* __restrict__ Crow16,
                                         const float* dvec, int lane) {
    const half8_t* Crow = (const half8_t*)Crow16;
    const float4* db = (const float4*)dvec;
    float a[32];
    float m = -1e30f;
#pragma unroll
    for (int c = 0; c < 4; ++c) {
        int base = (c << 6) + lane;
        half8_t ch = Crow[base];
        float4 f0 = db[2 * base];
        float4 f1 = db[2 * base + 1];
        float* ap = a + (c << 3);
        ap[0] = (f0.x - (float)ch[0]) * INV_EPS;
        ap[1] = (f0.y - (float)ch[1]) * INV_EPS;
        ap[2] = (f0.z - (float)ch[2]) * INV_EPS;
        ap[3] = (f0.w - (float)ch[3]) * INV_EPS;
        ap[4] = (f1.x - (float)ch[4]) * INV_EPS;
        ap[5] = (f1.y - (float)ch[5]) * INV_EPS;
        ap[6] = (f1.z - (float)ch[6]) * INV_EPS;
        ap[7] = (f1.w - (float)ch[7]) * INV_EPS;
#pragma unroll
        for (int q = 0; q < 8; ++q) m = fmaxf(m, ap[q]);
    }
#pragma unroll
    for (int off = 1; off < 64; off <<= 1) m = fmaxf(m, __shfl_xor(m, off));
    float s = 0.f;
#pragma unroll
    for (int q = 0; q < 32; ++q) s += __expf(a[q] - m);
#pragma unroll
    for (int off = 1; off < 64; off <<= 1) s += __shfl_xor(s, off);
    return EPSV * (LOG_MU_NU - m - __logf(s));
}

// ---------------- u update v2: v staged in LDS, 8 rows/block, grid 2048 ----------------
__global__ __launch_bounds__(256) void k_u2(const _Float16* __restrict__ C16,
                                            float* __restrict__ ws, int it) {
    if (load_done(ws) < it) return;
    __shared__ float vlds[2048];
    __shared__ float ered[4];
    float* u = ws + WS_U;
    const float* v = ws + WS_V;
    int b = blockIdx.x >> 8;           // 256 blocks per batch
    int rb = (blockIdx.x & 255) << 3;  // 8 rows per block
    int t = threadIdx.x;
    const float4* vsrc = (const float4*)(v + (b << 11));
    float4* vd = (float4*)vlds;
    vd[t] = vsrc[t];
    vd[t + 256] = vsrc[t + 256];
    __syncthreads();
    int wid = t >> 6, lane = t & 63;
    float eacc = 0.f;
#pragma unroll 1
    for (int rr = 0; rr < 2; ++rr) {
        int r = (b << 11) + rb + wid * 2 + rr;
        float unew = lse_row(C16 + ((size_t)r << 11), vlds, lane);
        if (lane == 0) {
            eacc += fabsf(unew - u[r]);
            u[r] = unew;
        }
    }
    if (lane == 0) ered[wid] = eacc;
    __syncthreads();
    if (t == 0) atomicAdd(ws + WS_ERR, ered[0] + ered[1] + ered[2] + ered[3]);
}

// ---------------- v update v2: u staged in LDS, reads CT rows ----------------
__global__ __launch_bounds__(256) void k_v2(const _Float16* __restrict__ CT,
                                            float* __restrict__ ws, int it) {
    if (load_done(ws) < it) return;
    check_prologue(ws, it);
    __shared__ float ulds[2048];
    const float* u = ws + WS_U;
    float* v = ws + WS_V;
    int b = blockIdx.x >> 8;
    int rb = (blockIdx.x & 255) << 3;
    int t = threadIdx.x;
    const float4* usrc = (const float4*)(u + (b << 11));
    float4* ud = (float4*)ulds;
    ud[t] = usrc[t];
    ud[t + 256] = usrc[t + 256];
    __syncthreads();
    int wid = t >> 6, lane = t & 63;
#pragma unroll 1
    for (int rr = 0; rr < 2; ++rr) {
        int r = (b << 11) + rb + wid * 2 + rr;
        float vnew = lse_row(CT + ((size_t)r << 11), ulds, lane);
        if (lane == 0) v[r] = vnew;
    }
}

// ---------------- fallback fp32 iteration kernels (small ws) ----------------
__global__ __launch_bounds__(256) void k_urow(const float* __restrict__ out,
                                              float* __restrict__ ws, int it) {
    if (load_done(ws) < it) return;
    float* u = ws + WS_U;
    const float* v = ws + WS_V;
    float* err = ws + WS_ERR;
    const float* C = out + OUT_C;
    int gw = (blockIdx.x * 256 + threadIdx.x) >> 6;
    int lane = threadIdx.x & 63;
    float eacc = 0.f;
    for (int r = gw; r < 16384; r += 4096) {
        int b = r >> 11;
        const float4* Crow = (const float4*)(C + ((size_t)r << 11));
        const float4* vb = (const float4*)(v + (b << 11));
        float a[32];
        float m = -1e30f;
#pragma unroll
        for (int c = 0; c < 8; ++c) {
            float4 cf = Crow[(c << 6) + lane];
            float4 vf = vb[(c << 6) + lane];
            a[4 * c + 0] = (vf.x - cf.x) * INV_EPS;
            a[4 * c + 1] = (vf.y - cf.y) * INV_EPS;
            a[4 * c + 2] = (vf.z - cf.z) * INV_EPS;
            a[4 * c + 3] = (vf.w - cf.w) * INV_EPS;
            m = fmaxf(m, fmaxf(fmaxf(a[4 * c + 0], a[4 * c + 1]), fmaxf(a[4 * c + 2], a[4 * c + 3])));
        }
#pragma unroll
        for (int off = 1; off < 64; off <<= 1) m = fmaxf(m, __shfl_xor(m, off));
        float s = 0.f;
#pragma unroll
        for (int q = 0; q < 32; ++q) s += __expf(a[q] - m);
#pragma unroll
        for (int off = 1; off < 64; off <<= 1) s += __shfl_xor(s, off);
        float unew = EPSV * (LOG_MU_NU - m - __logf(s));
        if (lane == 0) {
            eacc += fabsf(unew - u[r]);
            u[r] = unew;
        }
    }
    if (lane == 0) atomicAdd(err, eacc);
}

__global__ __launch_bounds__(256) void k_vcol(const float* __restrict__ out,
                                              float* __restrict__ ws, int it) {
    if (load_done(ws) < it) return;
    check_prologue(ws, it);
    const float* u = ws + WS_U;
    float* v = ws + WS_V;
    __shared__ float lm[8][33];
    __shared__ float ls[8][33];
    int b = blockIdx.x >> 6;
    int cg = blockIdx.x & 63;
    int j0 = cg * 32;
    int t = threadIdx.x;
    int jl = t & 31, chunk = t >> 5;
    const float* Cc = out + OUT_C + ((size_t)b << 22) + j0 + jl;
    const float* ub = u + (b << 11);
    float m = -1e30f, s = 0.f;
    int ibase = chunk << 8;
#pragma unroll 4
    for (int ii = 0; ii < 256; ++ii) {
        int i = ibase + ii;
        float xv = (ub[i] - Cc[(size_t)i << 11]) * INV_EPS;
        float nm = fmaxf(m, xv);
        s = s * __expf(m - nm) + __expf(xv - nm);
        m = nm;
    }
    lm[chunk][jl] = m;
    ls[chunk][jl] = s;
    __syncthreads();
    if (t < 32) {
        float M = -1e30f;
#pragma unroll
        for (int c = 0; c < 8; ++c) M = fmaxf(M, lm[c][t]);
        float S = 0.f;
#pragma unroll
        for (int c = 0; c < 8; ++c) S += ls[c][t] * __expf(lm[c][t] - M);
        v[(b << 11) + j0 + t] = EPSV * (LOG_MU_NU - M - __logf(S));
    }
}

// ---------------- fused epilogue: recompute exact C tile, write C + pi, accumulate dis ----------------
__global__ __launch_bounds__(256) void k_epi2(const float* __restrict__ x,
                                              const float* __restrict__ y,
                                              const float* __restrict__ ws,
                                              float* __restrict__ out) {
    __shared__ float xsT[64][68];
    __shared__ float ysT[64][68];
    __shared__ float dls[16][68];
    int b = blockIdx.z;
    int i0 = blockIdx.y * 64, j0 = blockIdx.x * 64;
    int t = threadIdx.x;
    const float* xb = x + ((size_t)b << 17);
    const float* yb = y + ((size_t)b << 17);
#pragma unroll
    for (int l = 0; l < 4; ++l) {
        int idx = l * 256 + t;
        int row = idx >> 4, kq = idx & 15;
        float4 fx = ((const float4*)(xb + ((size_t)(i0 + row) << 6)))[kq];
        xsT[kq * 4 + 0][row] = fx.x;
        xsT[kq * 4 + 1][row] = fx.y;
        xsT[kq * 4 + 2][row] = fx.z;
        xsT[kq * 4 + 3][row] = fx.w;
        float4 fy = ((const float4*)(yb + ((size_t)(j0 + row) << 6)))[kq];
        ysT[kq * 4 + 0][row] = fy.x;
        ysT[kq * 4 + 1][row] = fy.y;
        ysT[kq * 4 + 2][row] = fy.z;
        ysT[kq * 4 + 3][row] = fy.w;
    }
    __syncthreads();
    int tx = t & 15, ty = t >> 4;
    float acc[4][4] = {};
#pragma unroll 4
    for (int k = 0; k < 64; ++k) {
        float4 xa = *(const float4*)(&xsT[k][ty << 2]);
        float4 yv = *(const float4*)(&ysT[k][tx << 2]);
        float xr[4] = {xa.x, xa.y, xa.z, xa.w};
        float yc[4] = {yv.x, yv.y, yv.z, yv.w};
#pragma unroll
        for (int r = 0; r < 4; ++r)
#pragma unroll
            for (int c = 0; c < 4; ++c) acc[r][c] = fmaf(xr[r], yc[c], acc[r][c]);
    }
    const float* x2 = ws + WS_X2;
    const float* y2 = ws + WS_Y2;
    const float* u = ws + WS_U;
    const float* v = ws + WS_V;
    float x2r[4], y2c[4], ur[4], vc[4];
#pragma unroll
    for (int r = 0; r < 4; ++r) {
        x2r[r] = x2[b * 2048 + i0 + ty * 4 + r];
        ur[r] = u[(b << 11) + i0 + ty * 4 + r];
    }
#pragma unroll
    for (int c = 0; c < 4; ++c) {
        y2c[c] = y2[b * 2048 + j0 + tx * 4 + c];
        vc[c] = v[(b << 11) + j0 + tx * 4 + c];
    }
    float* C = out + OUT_C + ((size_t)b << 22);
    float* pi = out + OUT_PI + ((size_t)b << 22);
    float dpart[4] = {0.f, 0.f, 0.f, 0.f};
#pragma unroll
    for (int r = 0; r < 4; ++r) {
        int i = i0 + ty * 4 + r;
        float4 cv, pv;
        float cs[4], ps[4];
#pragma unroll
        for (int c = 0; c < 4; ++c) {
            cs[c] = x2r[r] + y2c[c] - acc[r][c] * (2.0f / 64.0f);
            ps[c] = __expf((ur[r] + vc[c] - cs[c]) * INV_EPS);
            dpart[c] = fmaf(ps[c], cs[c], dpart[c]);
        }
        cv.x = cs[0]; cv.y = cs[1]; cv.z = cs[2]; cv.w = cs[3];
        pv.x = ps[0]; pv.y = ps[1]; pv.z = ps[2]; pv.w = ps[3];
        size_t eoff = ((size_t)i << 11) + j0 + tx * 4;
        *(float4*)(C + eoff) = cv;
        *(float4*)(pi + eoff) = pv;
    }
#pragma unroll
    for (int c = 0; c < 4; ++c) dls[ty][tx * 4 + c] = dpart[c];
    __syncthreads();
    if (t < 64) {
        float s = 0.f;
#pragma unroll
        for (int q = 0; q < 16; ++q) s += dls[q][t];
        atomicAdd(out + OUT_DIS + (b << 11) + j0 + t, s);
    }
}

// ---------------- old epilogue (fallback path, reads stored fp32 C) ----------------
__global__ __launch_bounds__(256) void k_epi(float* __restrict__ out, const float* __restrict__ ws) {
    int b = blockIdx.z, jg = blockIdx.x, ic = blockIdx.y;
    int j = jg * 256 + threadIdx.x;
    int i0 = ic * 128;
    const float* u = ws + WS_U;
    const float* v = ws + WS_V;
    const float* C = out + OUT_C + ((size_t)b << 22);
    float* pi = out + OUT_PI + ((size_t)b << 22);
    float vj = v[(b << 11) + j];
    float accd = 0.f;
#pragma unroll 4
    for (int r = 0; r < 128; ++r) {
        int i = i0 + r;
        size_t idx = ((size_t)i << 11) + j;
        float cv = C[idx];
        float p = __expf((u[(b << 11) + i] + vj - cv) * INV_EPS);
        pi[idx] = p;
        accd = fmaf(p, cv, accd);
    }
    atomicAdd(out + OUT_DIS + (b << 11) + j, accd);
}

// ---------------- cost_b = sum_j dis_bj ----------------
__global__ void k_cost(float* __restrict__ out) {
    int b = blockIdx.x;
    float s = 0.f;
    for (int j = threadIdx.x; j < 2048; j += 256) s += out[OUT_DIS + (b << 11) + j];
#pragma unroll
    for (int off = 1; off < 64; off <<= 1) s += __shfl_xor(s, off);
    __shared__ float red[4];
    if ((threadIdx.x & 63) == 0) red[threadIdx.x >> 6] = s;
    __syncthreads();
    if (threadIdx.x == 0) out[OUT_COST + b] = red[0] + red[1] + red[2] + red[3];
}

extern "C" void kernel_launch(void* const* d_in, const int* in_sizes, int n_in,
                              void* d_out, int out_size, void* d_ws, size_t ws_size,
                              hipStream_t stream) {
    const float* x = (const float*)d_in[0];
    const float* y = (const float*)d_in[1];
    float* out = (float*)d_out;
    float* ws = (float*)d_ws;

    bool useCT = ws_size >= WS_CT_BYTE + C16_BYTES;
    _Float16* c16 = useCT ? (_Float16*)((char*)d_ws + WS_C16_BYTE) : nullptr;
    _Float16* c16T = useCT ? (_Float16*)((char*)d_ws + WS_CT_BYTE) : nullptr;

    k_init<<<64, 256, 0, stream>>>(ws, out);
    k_sqnorm<<<2048, 256, 0, stream>>>(x, y, ws);
    k_gemm<<<dim3(32, 32, 8), 256, 0, stream>>>(x, y, ws, out, c16, c16T, useCT ? 0 : 1);

    if (useCT) {
        for (int it = 0; it < MAX_ITER; ++it) {
            k_u2<<<2048, 256, 0, stream>>>(c16, ws, it);
            k_v2<<<2048, 256, 0, stream>>>(c16T, ws, it);
        }
        k_epi2<<<dim3(32, 32, 8), 256, 0, stream>>>(x, y, ws, out);
    } else {
        for (int it = 0; it < MAX_ITER; ++it) {
            k_urow<<<1024, 256, 0, stream>>>(out, ws, it);
            k_vcol<<<512, 256, 0, stream>>>(out, ws, it);
        }
        k_epi<<<dim3(8, 16, 8), 256, 0, stream>>>(out, ws);
    }
    k_cost<<<8, 256, 0, stream>>>(out);
}

// Round 4
// 1078.270 us; speedup vs baseline: 1.5691x; 1.1151x over previous
//
#include <hip/hip_runtime.h>
#include <cstddef>

#define EPSV 0.1f
#define INV_EPS 10.0f
#define THRESHV 0.1f
#define MAX_ITER 100
// log(1/2048 + 1e-8)
#define LOG_MU_NU (-7.6245985f)
// INV_EPS * log2(e)
#define SCALE_LOG2 14.4269504f
// EPSV * LOG_MU_NU
#define EPS_LMU (-0.76245985f)
// EPSV * ln(2)
#define EPS_LN2 0.069314718f

typedef _Float16 half4_t __attribute__((ext_vector_type(4)));
typedef _Float16 half8_t __attribute__((ext_vector_type(8)));

// ---- workspace layout (float offsets) ----
#define WS_U 0
#define WS_V 16384
#define WS_X2 32768
#define WS_Y2 49152
#define WS_ERR 65536
#define WS_DONE 65537  // int: iteration index at which convergence triggered (INT_MAX = not yet)
#define WS_C16_BYTE 327680ull
#define C16_BYTES (33554432ull * 2ull)
#define WS_CT_BYTE (WS_C16_BYTE + C16_BYTES)

// ---- output layout (float offsets): dis[8][2048], cost[8], pi[8][2048][2048], C[8][2048][2048]
#define OUT_DIS 0
#define OUT_COST 16384
#define OUT_PI 16392ull
#define OUT_C 33570824ull

__device__ __forceinline__ int load_done(const float* ws) {
    return __hip_atomic_load((int*)ws + WS_DONE, __ATOMIC_RELAXED, __HIP_MEMORY_SCOPE_AGENT);
}

// Convergence check in v-kernel prologue: err was finalized by the u-kernel (previous
// dispatch). Benign race: at the triggering iteration both INT_MAX and `it` fail the
// `< it` early-exit, so v still commits this iteration (matches reference).
__device__ __forceinline__ void check_prologue(float* ws, int it) {
    if (blockIdx.x == 0 && threadIdx.x == 0) {
        float e = ws[WS_ERR] * (1.0f / 8.0f);
        if (e < THRESHV)
            __hip_atomic_store((int*)ws + WS_DONE, it, __ATOMIC_RELAXED, __HIP_MEMORY_SCOPE_AGENT);
        ws[WS_ERR] = 0.f;
    }
}

// ---------------- init ----------------
__global__ void k_init(float* __restrict__ ws, float* __restrict__ out) {
    int idx = blockIdx.x * 256 + threadIdx.x;
    if (idx < 16384) {
        ws[WS_U + idx] = 0.f;
        ws[WS_V + idx] = 0.f;
        out[OUT_DIS + idx] = 0.f;
    }
    if (idx < 8) out[OUT_COST + idx] = 0.f;
    if (idx == 0) {
        ws[WS_ERR] = 0.f;
        ((int*)ws)[WS_DONE] = 0x7fffffff;
    }
}

// ---------------- x2 / y2: mean of squares over D=64 ----------------
__global__ __launch_bounds__(256) void k_sqnorm(const float* __restrict__ x,
                                                const float* __restrict__ y,
                                                float* __restrict__ ws) {
    int gid = blockIdx.x * 256 + threadIdx.x;
    int row = gid >> 4;
    int l = gid & 15;
    const float* src = (row < 16384) ? x : y;
    int r = row & 16383;
    float4 f = ((const float4*)(src + ((size_t)r << 6)))[l];
    float s = f.x * f.x + f.y * f.y + f.z * f.z + f.w * f.w;
    s += __shfl_xor(s, 1);
    s += __shfl_xor(s, 2);
    s += __shfl_xor(s, 4);
    s += __shfl_xor(s, 8);
    if (l == 0) ws[WS_X2 + row] = s * (1.0f / 64.0f);
}

// ---------------- k_gemm: C16 + CT (fp16); fp32 C only in fallback mode ----------------
__global__ __launch_bounds__(256) void k_gemm(const float* __restrict__ x,
                                              const float* __restrict__ y,
                                              const float* __restrict__ ws,
                                              float* __restrict__ out,
                                              _Float16* __restrict__ c16,
                                              _Float16* __restrict__ c16T,
                                              int wc32) {
    __shared__ float xsT[64][68];
    __shared__ float ysT[64][68];
    int b = blockIdx.z;
    int i0 = blockIdx.y * 64, j0 = blockIdx.x * 64;
    int t = threadIdx.x;
    const float* xb = x + ((size_t)b << 17);
    const float* yb = y + ((size_t)b << 17);
#pragma unroll
    for (int l = 0; l < 4; ++l) {
        int idx = l * 256 + t;
        int row = idx >> 4, kq = idx & 15;
        float4 fx = ((const float4*)(xb + ((size_t)(i0 + row) << 6)))[kq];
        xsT[kq * 4 + 0][row] = fx.x;
        xsT[kq * 4 + 1][row] = fx.y;
        xsT[kq * 4 + 2][row] = fx.z;
        xsT[kq * 4 + 3][row] = fx.w;
        float4 fy = ((const float4*)(yb + ((size_t)(j0 + row) << 6)))[kq];
        ysT[kq * 4 + 0][row] = fy.x;
        ysT[kq * 4 + 1][row] = fy.y;
        ysT[kq * 4 + 2][row] = fy.z;
        ysT[kq * 4 + 3][row] = fy.w;
    }
    __syncthreads();
    int tx = t & 15, ty = t >> 4;
    float acc[4][4] = {};
#pragma unroll 4
    for (int k = 0; k < 64; ++k) {
        float4 xa = *(const float4*)(&xsT[k][ty << 2]);
        float4 yv = *(const float4*)(&ysT[k][tx << 2]);
        float xr[4] = {xa.x, xa.y, xa.z, xa.w};
        float yc[4] = {yv.x, yv.y, yv.z, yv.w};
#pragma unroll
        for (int r = 0; r < 4; ++r)
#pragma unroll
            for (int c = 0; c < 4; ++c) acc[r][c] = fmaf(xr[r], yc[c], acc[r][c]);
    }
    const float* x2 = ws + WS_X2;
    const float* y2 = ws + WS_Y2;
    float x2r[4], y2c[4];
#pragma unroll
    for (int r = 0; r < 4; ++r) x2r[r] = x2[b * 2048 + i0 + ty * 4 + r];
#pragma unroll
    for (int c = 0; c < 4; ++c) y2c[c] = y2[b * 2048 + j0 + tx * 4 + c];
    float cvf[4][4];
#pragma unroll
    for (int r = 0; r < 4; ++r)
#pragma unroll
        for (int c = 0; c < 4; ++c) cvf[r][c] = x2r[r] + y2c[c] - acc[r][c] * (2.0f / 64.0f);

    float* C = out + OUT_C;
#pragma unroll
    for (int r = 0; r < 4; ++r) {
        int i = i0 + ty * 4 + r;
        size_t eoff = ((((size_t)b << 11) + i) << 11) + j0 + tx * 4;
        if (wc32) {
            float4 cv;
            cv.x = cvf[r][0];
            cv.y = cvf[r][1];
            cv.z = cvf[r][2];
            cv.w = cvf[r][3];
            *(float4*)(C + eoff) = cv;
        }
        if (c16) {
            half4_t h;
            h[0] = (_Float16)cvf[r][0];
            h[1] = (_Float16)cvf[r][1];
            h[2] = (_Float16)cvf[r][2];
            h[3] = (_Float16)cvf[r][3];
            *(half4_t*)(c16 + eoff) = h;
        }
    }
    if (c16T) {
#pragma unroll
        for (int c = 0; c < 4; ++c) {
            half4_t h;
            h[0] = (_Float16)cvf[0][c];
            h[1] = (_Float16)cvf[1][c];
            h[2] = (_Float16)cvf[2][c];
            h[3] = (_Float16)cvf[3][c];
            size_t toff = (((size_t)(b << 11) + j0 + tx * 4 + c) << 11) + i0 + ty * 4;
            *(half4_t*)(c16T + toff) = h;
        }
    }
}

// ---- single-pass max-free row LSE-sum with dual vector pre-scaled in registers ----
// Safe: exp2 args in [-115, +20] for this problem (C in [0,~5], potentials O(1)) —
// no overflow/underflow in fp32; differs from max-subtracted LSE only by rounding.
__device__ __forceinline__ float row_sum_exp(const _Float16* __restrict__ Crow16,
                                             const float vs[32], int lane) {
    const half8_t* Crow = (const half8_t*)Crow16;
    float sc[4];
#pragma unroll
    for (int c = 0; c < 4; ++c) {
        half8_t ch = Crow[(c << 6) + lane];
        float s0 = 0.f, s1 = 0.f;
#pragma unroll
        for (int q = 0; q < 4; ++q) {
            s0 += __builtin_exp2f(fmaf((float)ch[2 * q], -SCALE_LOG2, vs[(c << 3) + 2 * q]));
            s1 += __builtin_exp2f(fmaf((float)ch[2 * q + 1], -SCALE_LOG2, vs[(c << 3) + 2 * q + 1]));
        }
        sc[c] = s0 + s1;
    }
    float s = (sc[0] + sc[1]) + (sc[2] + sc[3]);
#pragma unroll
    for (int off = 1; off < 64; off <<= 1) s += __shfl_xor(s, off);
    return s;
}

// load dual vector (32 elems/lane) pre-scaled by SCALE_LOG2; layout matches half8 stream
__device__ __forceinline__ void load_dual(const float* __restrict__ dvec, float vs[32], int lane) {
    const float4* d4 = (const float4*)dvec;
#pragma unroll
    for (int c = 0; c < 4; ++c) {
        int base = (c << 6) + lane;
        float4 f0 = d4[2 * base];
        float4 f1 = d4[2 * base + 1];
        vs[(c << 3) + 0] = f0.x * SCALE_LOG2;
        vs[(c << 3) + 1] = f0.y * SCALE_LOG2;
        vs[(c << 3) + 2] = f0.z * SCALE_LOG2;
        vs[(c << 3) + 3] = f0.w * SCALE_LOG2;
        vs[(c << 3) + 4] = f1.x * SCALE_LOG2;
        vs[(c << 3) + 5] = f1.y * SCALE_LOG2;
        vs[(c << 3) + 6] = f1.z * SCALE_LOG2;
        vs[(c << 3) + 7] = f1.w * SCALE_LOG2;
    }
}

// ---------------- u update: wave owns 4 rows of ONE batch, v in registers ----------------
__global__ __launch_bounds__(256) void k_u3(const _Float16* __restrict__ C16,
                                            float* __restrict__ ws, int it) {
    if (load_done(ws) < it) return;
    float* u = ws + WS_U;
    const float* v = ws + WS_V;
    int gw = (blockIdx.x * 256 + threadIdx.x) >> 6;
    int lane = threadIdx.x & 63;
    int b = gw >> 9;  // 512 waves per batch
    float vs[32];
    load_dual(v + (b << 11), vs, lane);
    float eacc = 0.f;
#pragma unroll 1
    for (int rr = (gw & 511); rr < 2048; rr += 512) {
        int r = (b << 11) + rr;
        float s = row_sum_exp(C16 + ((size_t)r << 11), vs, lane);
        float unew = EPS_LMU - EPS_LN2 * __log2f(s);
        if (lane == 0) {
            eacc += fabsf(unew - u[r]);
            u[r] = unew;
        }
    }
    if (lane == 0) atomicAdd(ws + WS_ERR, eacc);
}

// ---------------- v update: wave owns 4 rows of CT, u in registers ----------------
__global__ __launch_bounds__(256) void k_v3(const _Float16* __restrict__ CT,
                                            float* __restrict__ ws, int it) {
    if (load_done(ws) < it) return;
    check_prologue(ws, it);
    const float* u = ws + WS_U;
    float* v = ws + WS_V;
    int gw = (blockIdx.x * 256 + threadIdx.x) >> 6;
    int lane = threadIdx.x & 63;
    int b = gw >> 9;
    float us[32];
    load_dual(u + (b << 11), us, lane);
#pragma unroll 1
    for (int rr = (gw & 511); rr < 2048; rr += 512) {
        int r = (b << 11) + rr;
        float s = row_sum_exp(CT + ((size_t)r << 11), us, lane);
        if (lane == 0) v[r] = EPS_LMU - EPS_LN2 * __log2f(s);
    }
}

// ---------------- fallback fp32 iteration kernels (small ws) ----------------
__global__ __launch_bounds__(256) void k_urow(const float* __restrict__ out,
                                              float* __restrict__ ws, int it) {
    if (load_done(ws) < it) return;
    float* u = ws + WS_U;
    const float* v = ws + WS_V;
    float* err = ws + WS_ERR;
    const float* C = out + OUT_C;
    int gw = (blockIdx.x * 256 + threadIdx.x) >> 6;
    int lane = threadIdx.x & 63;
    float eacc = 0.f;
    for (int r = gw; r < 16384; r += 4096) {
        int b = r >> 11;
        const float4* Crow = (const float4*)(C + ((size_t)r << 11));
        const float4* vb = (const float4*)(v + (b << 11));
        float a[32];
        float m = -1e30f;
#pragma unroll
        for (int c = 0; c < 8; ++c) {
            float4 cf = Crow[(c << 6) + lane];
            float4 vf = vb[(c << 6) + lane];
            a[4 * c + 0] = (vf.x - cf.x) * INV_EPS;
            a[4 * c + 1] = (vf.y - cf.y) * INV_EPS;
            a[4 * c + 2] = (vf.z - cf.z) * INV_EPS;
            a[4 * c + 3] = (vf.w - cf.w) * INV_EPS;
            m = fmaxf(m, fmaxf(fmaxf(a[4 * c + 0], a[4 * c + 1]), fmaxf(a[4 * c + 2], a[4 * c + 3])));
        }
#pragma unroll
        for (int off = 1; off < 64; off <<= 1) m = fmaxf(m, __shfl_xor(m, off));
        float s = 0.f;
#pragma unroll
        for (int q = 0; q < 32; ++q) s += __expf(a[q] - m);
#pragma unroll
        for (int off = 1; off < 64; off <<= 1) s += __shfl_xor(s, off);
        float unew = EPSV * (LOG_MU_NU - m - __logf(s));
        if (lane == 0) {
            eacc += fabsf(unew - u[r]);
            u[r] = unew;
        }
    }
    if (lane == 0) atomicAdd(err, eacc);
}

__global__ __launch_bounds__(256) void k_vcol(const float* __restrict__ out,
                                              float* __restrict__ ws, int it) {
    if (load_done(ws) < it) return;
    check_prologue(ws, it);
    const float* u = ws + WS_U;
    float* v = ws + WS_V;
    __shared__ float lm[8][33];
    __shared__ float ls[8][33];
    int b = blockIdx.x >> 6;
    int cg = blockIdx.x & 63;
    int j0 = cg * 32;
    int t = threadIdx.x;
    int jl = t & 31, chunk = t >> 5;
    const float* Cc = out + OUT_C + ((size_t)b << 22) + j0 + jl;
    const float* ub = u + (b << 11);
    float m = -1e30f, s = 0.f;
    int ibase = chunk << 8;
#pragma unroll 4
    for (int ii = 0; ii < 256; ++ii) {
        int i = ibase + ii;
        float xv = (ub[i] - Cc[(size_t)i << 11]) * INV_EPS;
        float nm = fmaxf(m, xv);
        s = s * __expf(m - nm) + __expf(xv - nm);
        m = nm;
    }
    lm[chunk][jl] = m;
    ls[chunk][jl] = s;
    __syncthreads();
    if (t < 32) {
        float M = -1e30f;
#pragma unroll
        for (int c = 0; c < 8; ++c) M = fmaxf(M, lm[c][t]);
        float S = 0.f;
#pragma unroll
        for (int c = 0; c < 8; ++c) S += ls[c][t] * __expf(lm[c][t] - M);
        v[(b << 11) + j0 + t] = EPSV * (LOG_MU_NU - M - __logf(S));
    }
}

// ---------------- fused epilogue: recompute exact C tile, write C + pi, accumulate dis ----------------
__global__ __launch_bounds__(256) void k_epi2(const float* __restrict__ x,
                                              const float* __restrict__ y,
                                              const float* __restrict__ ws,
                                              float* __restrict__ out) {
    __shared__ float xsT[64][68];
    __shared__ float ysT[64][68];
    __shared__ float dls[16][68];
    int b = blockIdx.z;
    int i0 = blockIdx.y * 64, j0 = blockIdx.x * 64;
    int t = threadIdx.x;
    const float* xb = x + ((size_t)b << 17);
    const float* yb = y + ((size_t)b << 17);
#pragma unroll
    for (int l = 0; l < 4; ++l) {
        int idx = l * 256 + t;
        int row = idx >> 4, kq = idx & 15;
        float4 fx = ((const float4*)(xb + ((size_t)(i0 + row) << 6)))[kq];
        xsT[kq * 4 + 0][row] = fx.x;
        xsT[kq * 4 + 1][row] = fx.y;
        xsT[kq * 4 + 2][row] = fx.z;
        xsT[kq * 4 + 3][row] = fx.w;
        float4 fy = ((const float4*)(yb + ((size_t)(j0 + row) << 6)))[kq];
        ysT[kq * 4 + 0][row] = fy.x;
        ysT[kq * 4 + 1][row] = fy.y;
        ysT[kq * 4 + 2][row] = fy.z;
        ysT[kq * 4 + 3][row] = fy.w;
    }
    __syncthreads();
    int tx = t & 15, ty = t >> 4;
    float acc[4][4] = {};
#pragma unroll 4
    for (int k = 0; k < 64; ++k) {
        float4 xa = *(const float4*)(&xsT[k][ty << 2]);
        float4 yv = *(const float4*)(&ysT[k][tx << 2]);
        float xr[4] = {xa.x, xa.y, xa.z, xa.w};
        float yc[4] = {yv.x, yv.y, yv.z, yv.w};
#pragma unroll
        for (int r = 0; r < 4; ++r)
#pragma unroll
            for (int c = 0; c < 4; ++c) acc[r][c] = fmaf(xr[r], yc[c], acc[r][c]);
    }
    const float* x2 = ws + WS_X2;
    const float* y2 = ws + WS_Y2;
    const float* u = ws + WS_U;
    const float* v = ws + WS_V;
    float x2r[4], y2c[4], ur[4], vc[4];
#pragma unroll
    for (int r = 0; r < 4; ++r) {
        x2r[r] = x2[b * 2048 + i0 + ty * 4 + r];
        ur[r] = u[(b << 11) + i0 + ty * 4 + r];
    }
#pragma unroll
    for (int c = 0; c < 4; ++c) {
        y2c[c] = y2[b * 2048 + j0 + tx * 4 + c];
        vc[c] = v[(b << 11) + j0 + tx * 4 + c];
    }
    float* C = out + OUT_C + ((size_t)b << 22);
    float* pi = out + OUT_PI + ((size_t)b << 22);
    float dpart[4] = {0.f, 0.f, 0.f, 0.f};
#pragma unroll
    for (int r = 0; r < 4; ++r) {
        int i = i0 + ty * 4 + r;
        float4 cv, pv;
        float cs[4], ps[4];
#pragma unroll
        for (int c = 0; c < 4; ++c) {
            cs[c] = x2r[r] + y2c[c] - acc[r][c] * (2.0f / 64.0f);
            ps[c] = __expf((ur[r] + vc[c] - cs[c]) * INV_EPS);
            dpart[c] = fmaf(ps[c], cs[c], dpart[c]);
        }
        cv.x = cs[0]; cv.y = cs[1]; cv.z = cs[2]; cv.w = cs[3];
        pv.x = ps[0]; pv.y = ps[1]; pv.z = ps[2]; pv.w = ps[3];
        size_t eoff = ((size_t)i << 11) + j0 + tx * 4;
        *(float4*)(C + eoff) = cv;
        *(float4*)(pi + eoff) = pv;
    }
#pragma unroll
    for (int c = 0; c < 4; ++c) dls[ty][tx * 4 + c] = dpart[c];
    __syncthreads();
    if (t < 64) {
        float s = 0.f;
#pragma unroll
        for (int q = 0; q < 16; ++q) s += dls[q][t];
        atomicAdd(out + OUT_DIS + (b << 11) + j0 + t, s);
    }
}

// ---------------- old epilogue (fallback path, reads stored fp32 C) ----------------
__global__ __launch_bounds__(256) void k_epi(float* __restrict__ out, const float* __restrict__ ws) {
    int b = blockIdx.z, jg = blockIdx.x, ic = blockIdx.y;
    int j = jg * 256 + threadIdx.x;
    int i0 = ic * 128;
    const float* u = ws + WS_U;
    const float* v = ws + WS_V;
    const float* C = out + OUT_C + ((size_t)b << 22);
    float* pi = out + OUT_PI + ((size_t)b << 22);
    float vj = v[(b << 11) + j];
    float accd = 0.f;
#pragma unroll 4
    for (int r = 0; r < 128; ++r) {
        int i = i0 + r;
        size_t idx = ((size_t)i << 11) + j;
        float cv = C[idx];
        float p = __expf((u[(b << 11) + i] + vj - cv) * INV_EPS);
        pi[idx] = p;
        accd = fmaf(p, cv, accd);
    }
    atomicAdd(out + OUT_DIS + (b << 11) + j, accd);
}

// ---------------- cost_b = sum_j dis_bj ----------------
__global__ void k_cost(float* __restrict__ out) {
    int b = blockIdx.x;
    float s = 0.f;
    for (int j = threadIdx.x; j < 2048; j += 256) s += out[OUT_DIS + (b << 11) + j];
#pragma unroll
    for (int off = 1; off < 64; off <<= 1) s += __shfl_xor(s, off);
    __shared__ float red[4];
    if ((threadIdx.x & 63) == 0) red[threadIdx.x >> 6] = s;
    __syncthreads();
    if (threadIdx.x == 0) out[OUT_COST + b] = red[0] + red[1] + red[2] + red[3];
}

extern "C" void kernel_launch(void* const* d_in, const int* in_sizes, int n_in,
                              void* d_out, int out_size, void* d_ws, size_t ws_size,
                              hipStream_t stream) {
    const float* x = (const float*)d_in[0];
    const float* y = (const float*)d_in[1];
    float* out = (float*)d_out;
    float* ws = (float*)d_ws;

    bool useCT = ws_size >= WS_CT_BYTE + C16_BYTES;
    _Float16* c16 = useCT ? (_Float16*)((char*)d_ws + WS_C16_BYTE) : nullptr;
    _Float16* c16T = useCT ? (_Float16*)((char*)d_ws + WS_CT_BYTE) : nullptr;

    k_init<<<64, 256, 0, stream>>>(ws, out);
    k_sqnorm<<<2048, 256, 0, stream>>>(x, y, ws);
    k_gemm<<<dim3(32, 32, 8), 256, 0, stream>>>(x, y, ws, out, c16, c16T, useCT ? 0 : 1);

    if (useCT) {
        for (int it = 0; it < MAX_ITER; ++it) {
            k_u3<<<1024, 256, 0, stream>>>(c16, ws, it);
            k_v3<<<1024, 256, 0, stream>>>(c16T, ws, it);
        }
        k_epi2<<<dim3(32, 32, 8), 256, 0, stream>>>(x, y, ws, out);
    } else {
        for (int it = 0; it < MAX_ITER; ++it) {
            k_urow<<<1024, 256, 0, stream>>>(out, ws, it);
            k_vcol<<<512, 256, 0, stream>>>(out, ws, it);
        }
        k_epi<<<dim3(8, 16, 8), 256, 0, stream>>>(out, ws);
    }
    k_cost<<<8, 256, 0, stream>>>(out);
}

// Round 5
// 842.927 us; speedup vs baseline: 2.0072x; 1.2792x over previous
//
#include <hip/hip_runtime.h>
#include <cstddef>

#define EPSV 0.1f
#define INV_EPS 10.0f
#define THRESHV 0.1f
#define MAX_ITER 100
// log(1/2048 + 1e-8)
#define LOG_MU_NU (-7.6245985f)
// INV_EPS * log2(e)
#define SCALE_LOG2 14.4269504f
// EPSV * LOG_MU_NU
#define EPS_LMU (-0.76245985f)
// EPSV * ln(2)
#define EPS_LN2 0.069314718f
// exp(LOG_MU_NU) = 1/2048 + 1e-8
#define MU_CONST 4.8829125e-4f

typedef _Float16 half4_t __attribute__((ext_vector_type(4)));
typedef _Float16 half8_t __attribute__((ext_vector_type(8)));

// ---- workspace layout (float offsets) ----
#define WS_U 0
#define WS_V 16384
#define WS_X2 32768
#define WS_Y2 49152
#define WS_ERR 65536
#define WS_DONE 65537  // int: iteration index at which convergence triggered (INT_MAX = not yet)
#define WS_C16_BYTE 327680ull
#define C16_BYTES (33554432ull * 2ull)
// column-partial A arrays: part[512 blocks][2048 cols] fp32
#define WS_PART_BYTE (WS_C16_BYTE + C16_BYTES)
#define PART_BYTES (512ull * 2048ull * 4ull)

// ---- output layout (float offsets): dis[8][2048], cost[8], pi[8][2048][2048], C[8][2048][2048]
#define OUT_DIS 0
#define OUT_COST 16384
#define OUT_PI 16392ull
#define OUT_C 33570824ull

__device__ __forceinline__ int load_done(const float* ws) {
    return __hip_atomic_load((int*)ws + WS_DONE, __ATOMIC_RELAXED, __HIP_MEMORY_SCOPE_AGENT);
}

// Convergence check in the reduction-kernel prologue: err was finalized by k_uv
// (previous dispatch). Benign race: at the triggering iteration both INT_MAX and `it`
// fail the `< it` early-exit, so v still commits this iteration (matches reference:
// the triggering iteration commits u_new AND v_new; later iterations are frozen).
__device__ __forceinline__ void check_prologue(float* ws, int it) {
    if (blockIdx.x == 0 && threadIdx.x == 0) {
        float e = ws[WS_ERR] * (1.0f / 8.0f);
        if (e < THRESHV)
            __hip_atomic_store((int*)ws + WS_DONE, it, __ATOMIC_RELAXED, __HIP_MEMORY_SCOPE_AGENT);
        ws[WS_ERR] = 0.f;
    }
}

// ---------------- init ----------------
__global__ void k_init(float* __restrict__ ws, float* __restrict__ out) {
    int idx = blockIdx.x * 256 + threadIdx.x;
    if (idx < 16384) {
        ws[WS_U + idx] = 0.f;
        ws[WS_V + idx] = 0.f;
        out[OUT_DIS + idx] = 0.f;
    }
    if (idx < 8) out[OUT_COST + idx] = 0.f;
    if (idx == 0) {
        ws[WS_ERR] = 0.f;
        ((int*)ws)[WS_DONE] = 0x7fffffff;
    }
}

// ---------------- x2 / y2: mean of squares over D=64 ----------------
__global__ __launch_bounds__(256) void k_sqnorm(const float* __restrict__ x,
                                                const float* __restrict__ y,
                                                float* __restrict__ ws) {
    int gid = blockIdx.x * 256 + threadIdx.x;
    int row = gid >> 4;
    int l = gid & 15;
    const float* src = (row < 16384) ? x : y;
    int r = row & 16383;
    float4 f = ((const float4*)(src + ((size_t)r << 6)))[l];
    float s = f.x * f.x + f.y * f.y + f.z * f.z + f.w * f.w;
    s += __shfl_xor(s, 1);
    s += __shfl_xor(s, 2);
    s += __shfl_xor(s, 4);
    s += __shfl_xor(s, 8);
    if (l == 0) ws[WS_X2 + row] = s * (1.0f / 64.0f);
}

// ---------------- k_gemm: C16 (fp16); fp32 C only in fallback mode ----------------
__global__ __launch_bounds__(256) void k_gemm(const float* __restrict__ x,
                                              const float* __restrict__ y,
                                              const float* __restrict__ ws,
                                              float* __restrict__ out,
                                              _Float16* __restrict__ c16,
                                              int wc32) {
    __shared__ float xsT[64][68];
    __shared__ float ysT[64][68];
    int b = blockIdx.z;
    int i0 = blockIdx.y * 64, j0 = blockIdx.x * 64;
    int t = threadIdx.x;
    const float* xb = x + ((size_t)b << 17);
    const float* yb = y + ((size_t)b << 17);
#pragma unroll
    for (int l = 0; l < 4; ++l) {
        int idx = l * 256 + t;
        int row = idx >> 4, kq = idx & 15;
        float4 fx = ((const float4*)(xb + ((size_t)(i0 + row) << 6)))[kq];
        xsT[kq * 4 + 0][row] = fx.x;
        xsT[kq * 4 + 1][row] = fx.y;
        xsT[kq * 4 + 2][row] = fx.z;
        xsT[kq * 4 + 3][row] = fx.w;
        float4 fy = ((const float4*)(yb + ((size_t)(j0 + row) << 6)))[kq];
        ysT[kq * 4 + 0][row] = fy.x;
        ysT[kq * 4 + 1][row] = fy.y;
        ysT[kq * 4 + 2][row] = fy.z;
        ysT[kq * 4 + 3][row] = fy.w;
    }
    __syncthreads();
    int tx = t & 15, ty = t >> 4;
    float acc[4][4] = {};
#pragma unroll 4
    for (int k = 0; k < 64; ++k) {
        float4 xa = *(const float4*)(&xsT[k][ty << 2]);
        float4 yv = *(const float4*)(&ysT[k][tx << 2]);
        float xr[4] = {xa.x, xa.y, xa.z, xa.w};
        float yc[4] = {yv.x, yv.y, yv.z, yv.w};
#pragma unroll
        for (int r = 0; r < 4; ++r)
#pragma unroll
            for (int c = 0; c < 4; ++c) acc[r][c] = fmaf(xr[r], yc[c], acc[r][c]);
    }
    const float* x2 = ws + WS_X2;
    const float* y2 = ws + WS_Y2;
    float x2r[4], y2c[4];
#pragma unroll
    for (int r = 0; r < 4; ++r) x2r[r] = x2[b * 2048 + i0 + ty * 4 + r];
#pragma unroll
    for (int c = 0; c < 4; ++c) y2c[c] = y2[b * 2048 + j0 + tx * 4 + c];
    float cvf[4][4];
#pragma unroll
    for (int r = 0; r < 4; ++r)
#pragma unroll
        for (int c = 0; c < 4; ++c) cvf[r][c] = x2r[r] + y2c[c] - acc[r][c] * (2.0f / 64.0f);

    float* C = out + OUT_C;
#pragma unroll
    for (int r = 0; r < 4; ++r) {
        int i = i0 + ty * 4 + r;
        size_t eoff = ((((size_t)b << 11) + i) << 11) + j0 + tx * 4;
        if (wc32) {
            float4 cv;
            cv.x = cvf[r][0];
            cv.y = cvf[r][1];
            cv.z = cvf[r][2];
            cv.w = cvf[r][3];
            *(float4*)(C + eoff) = cv;
        }
        if (c16) {
            half4_t h;
            h[0] = (_Float16)cvf[r][0];
            h[1] = (_Float16)cvf[r][1];
            h[2] = (_Float16)cvf[r][2];
            h[3] = (_Float16)cvf[r][3];
            *(half4_t*)(c16 + eoff) = h;
        }
    }
}

// load dual vector (32 elems/lane) pre-scaled by SCALE_LOG2; layout matches half8 stream
__device__ __forceinline__ void load_dual(const float* __restrict__ dvec, float vs[32], int lane) {
    const float4* d4 = (const float4*)dvec;
#pragma unroll
    for (int c = 0; c < 4; ++c) {
        int base = (c << 6) + lane;
        float4 f0 = d4[2 * base];
        float4 f1 = d4[2 * base + 1];
        vs[(c << 3) + 0] = f0.x * SCALE_LOG2;
        vs[(c << 3) + 1] = f0.y * SCALE_LOG2;
        vs[(c << 3) + 2] = f0.z * SCALE_LOG2;
        vs[(c << 3) + 3] = f0.w * SCALE_LOG2;
        vs[(c << 3) + 4] = f1.x * SCALE_LOG2;
        vs[(c << 3) + 5] = f1.y * SCALE_LOG2;
        vs[(c << 3) + 6] = f1.z * SCALE_LOG2;
        vs[(c << 3) + 7] = f1.w * SCALE_LOG2;
    }
}

// ---------------- fused u-update + column-partial pass ----------------
// One pass over row-major C16 computes u_new (per-row LSE with v in registers) AND
// the column partials A_j = sum_i (MU/S_i) * t_ij, reusing the already-computed
// t_ij = exp((v_j - C_ij)/eps). Gauss-Seidel preserved:
//   v_new_j = eps*log_nu - eps*ln(A_j) + v_j   (finalized by k_vred).
// Grid: 8 batches x 64 blocks; 4 waves/block; 8 rows/wave (rows wv + 256k).
__global__ __launch_bounds__(256) void k_uv(const _Float16* __restrict__ C16,
                                            float* __restrict__ ws,
                                            float* __restrict__ part, int it) {
    if (load_done(ws) < it) return;
    __shared__ float Als[4][2048];
    __shared__ float ered[4];
    float* u = ws + WS_U;
    const float* v = ws + WS_V;
    int b = blockIdx.x >> 6;
    int blk = blockIdx.x & 63;
    int w = threadIdx.x >> 6, lane = threadIdx.x & 63;
    int wv = (blk << 2) + w;  // wave index within batch [0,256)
    float vs[32];
    load_dual(v + (b << 11), vs, lane);
    float A[32];
#pragma unroll
    for (int q = 0; q < 32; ++q) A[q] = 0.f;
    float eacc = 0.f;
#pragma unroll 1
    for (int k = 0; k < 8; ++k) {
        int r = (b << 11) + wv + (k << 8);
        const half8_t* Crow = (const half8_t*)(C16 + ((size_t)r << 11));
        float t[32];
        float sg[4];
#pragma unroll
        for (int c = 0; c < 4; ++c) {
            half8_t ch = Crow[(c << 6) + lane];
            float* tp = t + (c << 3);
#pragma unroll
            for (int q = 0; q < 8; ++q)
                tp[q] = __builtin_exp2f(fmaf((float)ch[q], -SCALE_LOG2, vs[(c << 3) + q]));
            sg[c] = ((tp[0] + tp[1]) + (tp[2] + tp[3])) + ((tp[4] + tp[5]) + (tp[6] + tp[7]));
        }
        float s = (sg[0] + sg[1]) + (sg[2] + sg[3]);
#pragma unroll
        for (int off = 1; off < 64; off <<= 1) s += __shfl_xor(s, off);
        float wgt = MU_CONST / s;  // = exp(u_new/eps)
#pragma unroll
        for (int q = 0; q < 32; ++q) A[q] = fmaf(t[q], wgt, A[q]);
        float unew = EPS_LMU - EPS_LN2 * __log2f(s);
        if (lane == 0) {
            eacc += fabsf(unew - u[r]);
            u[r] = unew;
        }
    }
    if (lane == 0) ered[w] = eacc;
    // flush per-wave A to LDS: Als[w][j] is linear in batch-local column j
    // (lane's slots are j = 8*(c*64+lane)+q -> float offset (c*64+lane)*8+q)
    {
        float4* dst = (float4*)&Als[w][0];
#pragma unroll
        for (int c = 0; c < 4; ++c) {
            int f4 = ((c << 6) + lane) << 1;
            float4 p0, p1;
            p0.x = A[(c << 3) + 0];
            p0.y = A[(c << 3) + 1];
            p0.z = A[(c << 3) + 2];
            p0.w = A[(c << 3) + 3];
            p1.x = A[(c << 3) + 4];
            p1.y = A[(c << 3) + 5];
            p1.z = A[(c << 3) + 6];
            p1.w = A[(c << 3) + 7];
            dst[f4] = p0;
            dst[f4 + 1] = p1;
        }
    }
    __syncthreads();
    // block-reduce 4 waves and write this block's partial (coalesced)
    {
        int tt = threadIdx.x;
        float4 a0 = *(float4*)&Als[0][tt << 3];
        float4 a1 = *(float4*)&Als[1][tt << 3];
        float4 a2 = *(float4*)&Als[2][tt << 3];
        float4 a3 = *(float4*)&Als[3][tt << 3];
        float4 b0 = *(float4*)&Als[0][(tt << 3) + 4];
        float4 b1 = *(float4*)&Als[1][(tt << 3) + 4];
        float4 b2 = *(float4*)&Als[2][(tt << 3) + 4];
        float4 b3 = *(float4*)&Als[3][(tt << 3) + 4];
        float4 o0, o1;
        o0.x = (a0.x + a1.x) + (a2.x + a3.x);
        o0.y = (a0.y + a1.y) + (a2.y + a3.y);
        o0.z = (a0.z + a1.z) + (a2.z + a3.z);
        o0.w = (a0.w + a1.w) + (a2.w + a3.w);
        o1.x = (b0.x + b1.x) + (b2.x + b3.x);
        o1.y = (b0.y + b1.y) + (b2.y + b3.y);
        o1.z = (b0.z + b1.z) + (b2.z + b3.z);
        o1.w = (b0.w + b1.w) + (b2.w + b3.w);
        float* pd = part + (((size_t)blockIdx.x) << 11) + (tt << 3);
        *(float4*)pd = o0;
        *(float4*)(pd + 4) = o1;
        if (tt == 0) atomicAdd(ws + WS_ERR, ered[0] + ered[1] + ered[2] + ered[3]);
    }
}

// ---------------- v finalize: reduce 64 block-partials per batch, update v ----------------
// grid 64 = 8 batches x 8 segments; thread handles one column j.
__global__ __launch_bounds__(256) void k_vred(float* __restrict__ ws,
                                              const float* __restrict__ part, int it) {
    if (load_done(ws) < it) return;
    check_prologue(ws, it);
    int b = blockIdx.x >> 3;
    int j = ((blockIdx.x & 7) << 8) + threadIdx.x;
    const float* pb = part + ((size_t)b << 17) + j;
    float a0 = 0.f, a1 = 0.f, a2 = 0.f, a3 = 0.f;
#pragma unroll
    for (int blk = 0; blk < 64; blk += 4) {
        a0 += pb[(size_t)(blk + 0) << 11];
        a1 += pb[(size_t)(blk + 1) << 11];
        a2 += pb[(size_t)(blk + 2) << 11];
        a3 += pb[(size_t)(blk + 3) << 11];
    }
    float A = (a0 + a1) + (a2 + a3);
    float* v = ws + WS_V;
    int gj = (b << 11) + j;
    v[gj] = EPS_LMU - EPS_LN2 * __log2f(A) + v[gj];
}

// ---------------- fallback fp32 iteration kernels (small ws) ----------------
__global__ __launch_bounds__(256) void k_urow(const float* __restrict__ out,
                                              float* __restrict__ ws, int it) {
    if (load_done(ws) < it) return;
    float* u = ws + WS_U;
    const float* v = ws + WS_V;
    float* err = ws + WS_ERR;
    const float* C = out + OUT_C;
    int gw = (blockIdx.x * 256 + threadIdx.x) >> 6;
    int lane = threadIdx.x & 63;
    float eacc = 0.f;
    for (int r = gw; r < 16384; r += 4096) {
        int b = r >> 11;
        const float4* Crow = (const float4*)(C + ((size_t)r << 11));
        const float4* vb = (const float4*)(v + (b << 11));
        float a[32];
        float m = -1e30f;
#pragma unroll
        for (int c = 0; c < 8; ++c) {
            float4 cf = Crow[(c << 6) + lane];
            float4 vf = vb[(c << 6) + lane];
            a[4 * c + 0] = (vf.x - cf.x) * INV_EPS;
            a[4 * c + 1] = (vf.y - cf.y) * INV_EPS;
            a[4 * c + 2] = (vf.z - cf.z) * INV_EPS;
            a[4 * c + 3] = (vf.w - cf.w) * INV_EPS;
            m = fmaxf(m, fmaxf(fmaxf(a[4 * c + 0], a[4 * c + 1]), fmaxf(a[4 * c + 2], a[4 * c + 3])));
        }
#pragma unroll
        for (int off = 1; off < 64; off <<= 1) m = fmaxf(m, __shfl_xor(m, off));
        float s = 0.f;
#pragma unroll
        for (int q = 0; q < 32; ++q) s += __expf(a[q] - m);
#pragma unroll
        for (int off = 1; off < 64; off <<= 1) s += __shfl_xor(s, off);
        float unew = EPSV * (LOG_MU_NU - m - __logf(s));
        if (lane == 0) {
            eacc += fabsf(unew - u[r]);
            u[r] = unew;
        }
    }
    if (lane == 0) atomicAdd(err, eacc);
}

__global__ __launch_bounds__(256) void k_vcol(const float* __restrict__ out,
                                              float* __restrict__ ws, int it) {
    if (load_done(ws) < it) return;
    check_prologue(ws, it);
    const float* u = ws + WS_U;
    float* v = ws + WS_V;
    __shared__ float lm[8][33];
    __shared__ float ls[8][33];
    int b = blockIdx.x >> 6;
    int cg = blockIdx.x & 63;
    int j0 = cg * 32;
    int t = threadIdx.x;
    int jl = t & 31, chunk = t >> 5;
    const float* Cc = out + OUT_C + ((size_t)b << 22) + j0 + jl;
    const float* ub = u + (b << 11);
    float m = -1e30f, s = 0.f;
    int ibase = chunk << 8;
#pragma unroll 4
    for (int ii = 0; ii < 256; ++ii) {
        int i = ibase + ii;
        float xv = (ub[i] - Cc[(size_t)i << 11]) * INV_EPS;
        float nm = fmaxf(m, xv);
        s = s * __expf(m - nm) + __expf(xv - nm);
        m = nm;
    }
    lm[chunk][jl] = m;
    ls[chunk][jl] = s;
    __syncthreads();
    if (t < 32) {
        float M = -1e30f;
#pragma unroll
        for (int c = 0; c < 8; ++c) M = fmaxf(M, lm[c][t]);
        float S = 0.f;
#pragma unroll
        for (int c = 0; c < 8; ++c) S += ls[c][t] * __expf(lm[c][t] - M);
        v[(b << 11) + j0 + t] = EPSV * (LOG_MU_NU - M - __logf(S));
    }
}

// ---------------- fused epilogue: recompute exact C tile, write C + pi, accumulate dis ----------------
__global__ __launch_bounds__(256) void k_epi2(const float* __restrict__ x,
                                              const float* __restrict__ y,
                                              const float* __restrict__ ws,
                                              float* __restrict__ out) {
    __shared__ float xsT[64][68];
    __shared__ float ysT[64][68];
    __shared__ float dls[16][68];
    int b = blockIdx.z;
    int i0 = blockIdx.y * 64, j0 = blockIdx.x * 64;
    int t = threadIdx.x;
    const float* xb = x + ((size_t)b << 17);
    const float* yb = y + ((size_t)b << 17);
#pragma unroll
    for (int l = 0; l < 4; ++l) {
        int idx = l * 256 + t;
        int row = idx >> 4, kq = idx & 15;
        float4 fx = ((const float4*)(xb + ((size_t)(i0 + row) << 6)))[kq];
        xsT[kq * 4 + 0][row] = fx.x;
        xsT[kq * 4 + 1][row] = fx.y;
        xsT[kq * 4 + 2][row] = fx.z;
        xsT[kq * 4 + 3][row] = fx.w;
        float4 fy = ((const float4*)(yb + ((size_t)(j0 + row) << 6)))[kq];
        ysT[kq * 4 + 0][row] = fy.x;
        ysT[kq * 4 + 1][row] = fy.y;
        ysT[kq * 4 + 2][row] = fy.z;
        ysT[kq * 4 + 3][row] = fy.w;
    }
    __syncthreads();
    int tx = t & 15, ty = t >> 4;
    float acc[4][4] = {};
#pragma unroll 4
    for (int k = 0; k < 64; ++k) {
        float4 xa = *(const float4*)(&xsT[k][ty << 2]);
        float4 yv = *(const float4*)(&ysT[k][tx << 2]);
        float xr[4] = {xa.x, xa.y, xa.z, xa.w};
        float yc[4] = {yv.x, yv.y, yv.z, yv.w};
#pragma unroll
        for (int r = 0; r < 4; ++r)
#pragma unroll
            for (int c = 0; c < 4; ++c) acc[r][c] = fmaf(xr[r], yc[c], acc[r][c]);
    }
    const float* x2 = ws + WS_X2;
    const float* y2 = ws + WS_Y2;
    const float* u = ws + WS_U;
    const float* v = ws + WS_V;
    float x2r[4], y2c[4], ur[4], vc[4];
#pragma unroll
    for (int r = 0; r < 4; ++r) {
        x2r[r] = x2[b * 2048 + i0 + ty * 4 + r];
        ur[r] = u[(b << 11) + i0 + ty * 4 + r];
    }
#pragma unroll
    for (int c = 0; c < 4; ++c) {
        y2c[c] = y2[b * 2048 + j0 + tx * 4 + c];
        vc[c] = v[(b << 11) + j0 + tx * 4 + c];
    }
    float* C = out + OUT_C + ((size_t)b << 22);
    float* pi = out + OUT_PI + ((size_t)b << 22);
    float dpart[4] = {0.f, 0.f, 0.f, 0.f};
#pragma unroll
    for (int r = 0; r < 4; ++r) {
        int i = i0 + ty * 4 + r;
        float4 cv, pv;
        float cs[4], ps[4];
#pragma unroll
        for (int c = 0; c < 4; ++c) {
            cs[c] = x2r[r] + y2c[c] - acc[r][c] * (2.0f / 64.0f);
            ps[c] = __expf((ur[r] + vc[c] - cs[c]) * INV_EPS);
            dpart[c] = fmaf(ps[c], cs[c], dpart[c]);
        }
        cv.x = cs[0]; cv.y = cs[1]; cv.z = cs[2]; cv.w = cs[3];
        pv.x = ps[0]; pv.y = ps[1]; pv.z = ps[2]; pv.w = ps[3];
        size_t eoff = ((size_t)i << 11) + j0 + tx * 4;
        *(float4*)(C + eoff) = cv;
        *(float4*)(pi + eoff) = pv;
    }
#pragma unroll
    for (int c = 0; c < 4; ++c) dls[ty][tx * 4 + c] = dpart[c];
    __syncthreads();
    if (t < 64) {
        float s = 0.f;
#pragma unroll
        for (int q = 0; q < 16; ++q) s += dls[q][t];
        atomicAdd(out + OUT_DIS + (b << 11) + j0 + t, s);
    }
}

// ---------------- old epilogue (fallback path, reads stored fp32 C) ----------------
__global__ __launch_bounds__(256) void k_epi(float* __restrict__ out, const float* __restrict__ ws) {
    int b = blockIdx.z, jg = blockIdx.x, ic = blockIdx.y;
    int j = jg * 256 + threadIdx.x;
    int i0 = ic * 128;
    const float* u = ws + WS_U;
    const float* v = ws + WS_V;
    const float* C = out + OUT_C + ((size_t)b << 22);
    float* pi = out + OUT_PI + ((size_t)b << 22);
    float vj = v[(b << 11) + j];
    float accd = 0.f;
#pragma unroll 4
    for (int r = 0; r < 128; ++r) {
        int i = i0 + r;
        size_t idx = ((size_t)i << 11) + j;
        float cv = C[idx];
        float p = __expf((u[(b << 11) + i] + vj - cv) * INV_EPS);
        pi[idx] = p;
        accd = fmaf(p, cv, accd);
    }
    atomicAdd(out + OUT_DIS + (b << 11) + j, accd);
}

// ---------------- cost_b = sum_j dis_bj ----------------
__global__ void k_cost(float* __restrict__ out) {
    int b = blockIdx.x;
    float s = 0.f;
    for (int j = threadIdx.x; j < 2048; j += 256) s += out[OUT_DIS + (b << 11) + j];
#pragma unroll
    for (int off = 1; off < 64; off <<= 1) s += __shfl_xor(s, off);
    __shared__ float red[4];
    if ((threadIdx.x & 63) == 0) red[threadIdx.x >> 6] = s;
    __syncthreads();
    if (threadIdx.x == 0) out[OUT_COST + b] = red[0] + red[1] + red[2] + red[3];
}

extern "C" void kernel_launch(void* const* d_in, const int* in_sizes, int n_in,
                              void* d_out, int out_size, void* d_ws, size_t ws_size,
                              hipStream_t stream) {
    const float* x = (const float*)d_in[0];
    const float* y = (const float*)d_in[1];
    float* out = (float*)d_out;
    float* ws = (float*)d_ws;

    bool useP = ws_size >= WS_PART_BYTE + PART_BYTES;
    _Float16* c16 = useP ? (_Float16*)((char*)d_ws + WS_C16_BYTE) : nullptr;
    float* part = useP ? (float*)((char*)d_ws + WS_PART_BYTE) : nullptr;

    k_init<<<64, 256, 0, stream>>>(ws, out);
    k_sqnorm<<<2048, 256, 0, stream>>>(x, y, ws);
    k_gemm<<<dim3(32, 32, 8), 256, 0, stream>>>(x, y, ws, out, c16, useP ? 0 : 1);

    if (useP) {
        for (int it = 0; it < MAX_ITER; ++it) {
            k_uv<<<512, 256, 0, stream>>>(c16, ws, part, it);
            k_vred<<<64, 256, 0, stream>>>(ws, part, it);
        }
        k_epi2<<<dim3(32, 32, 8), 256, 0, stream>>>(x, y, ws, out);
    } else {
        for (int it = 0; it < MAX_ITER; ++it) {
            k_urow<<<1024, 256, 0, stream>>>(out, ws, it);
            k_vcol<<<512, 256, 0, stream>>>(out, ws, it);
        }
        k_epi<<<dim3(8, 16, 8), 256, 0, stream>>>(out, ws);
    }
    k_cost<<<8, 256, 0, stream>>>(out);
}